// Round 9
// baseline (3602.331 us; speedup 1.0000x reference)
//
#include <hip/hip_runtime.h>
#include <math.h>

#define B_    32
#define T_    256
#define HID_  512
#define G4_   2048   // 4*HID
#define VOC_  10000
#define NPAD_ 10112  // 79*128, padded vocab for the bf16 GEMM
#define BH_   (B_ * HID_)

typedef float f32x4 __attribute__((ext_vector_type(4)));
typedef short bf16x8 __attribute__((ext_vector_type(8)));
typedef unsigned short u16;
typedef u16 u16x8 __attribute__((ext_vector_type(8)));

#define AADD(p)  __hip_atomic_fetch_add((p), 1u, __ATOMIC_RELAXED, __HIP_MEMORY_SCOPE_AGENT)
#define ALOAD(p) __hip_atomic_load((p), __ATOMIC_RELAXED, __HIP_MEMORY_SCOPE_AGENT)

// ---------------- coherent (cross-XCD via IF$) helpers: sc0 sc1 ------------
__device__ __forceinline__ void load4_coherent(const float* p0, const float* p1,
                                               const float* p2, const float* p3,
                                               f32x4& a, f32x4& b, f32x4& c, f32x4& d)
{
    asm volatile(
        "global_load_dwordx4 %0, %4, off sc0 sc1\n\t"
        "global_load_dwordx4 %1, %5, off sc0 sc1\n\t"
        "global_load_dwordx4 %2, %6, off sc0 sc1\n\t"
        "global_load_dwordx4 %3, %7, off sc0 sc1\n\t"
        "s_waitcnt vmcnt(0)"
        : "=&v"(a), "=&v"(b), "=&v"(c), "=&v"(d)
        : "v"(p0), "v"(p1), "v"(p2), "v"(p3)
        : "memory");
}
__device__ __forceinline__ float load_coherent_f32(const float* p)
{
    float v;
    asm volatile("global_load_dword %0, %1, off sc0 sc1\n\ts_waitcnt vmcnt(0)"
                 : "=v"(v) : "v"(p) : "memory");
    return v;
}
__device__ __forceinline__ void store_coherent(float* p, float x)
{
    asm volatile("global_store_dword %0, %1, off sc0 sc1" :: "v"(p), "v"(x) : "memory");
}

__device__ __forceinline__ float fsigm(float x)
{
    float e = exp2f(x * -1.4426950408889634f);
    return __builtin_amdgcn_rcpf(1.f + e);
}
__device__ __forceinline__ float ftanh(float x)
{
    float e = exp2f(x * 2.8853900817779268f);
    return 1.f - 2.f * __builtin_amdgcn_rcpf(e + 1.f);
}

// fp32 -> bf16_hi + bf16_lo (RNE both; a ~= hi + lo with ~16 mantissa bits)
__device__ __forceinline__ void bsplit(float x, u16& hi, u16& lo)
{
    union { float f; unsigned u; } a; a.f = x;
    unsigned r = a.u + 0x7FFFu + ((a.u >> 16) & 1u);
    hi = (u16)(r >> 16);
    union { unsigned u; float f; } hf; hf.u = ((unsigned)hi) << 16;
    union { float f; unsigned u; } b; b.f = x - hf.f;
    unsigned r2 = b.u + 0x7FFFu + ((b.u >> 16) & 1u);
    lo = (u16)(r2 >> 16);
}

// spin until *p >= tgt (monotonic counter), with hang-safety bail  [r6-proven]
__device__ __forceinline__ void wait_ge(unsigned* p, unsigned tgt)
{
    unsigned g = 0;
    while (ALOAD(p) < tgt) {
        __builtin_amdgcn_s_sleep(2);
        if (++g > 100000000u) break;
    }
}

// ---------------------------------------------------------------------------
// Transpose + split: W [512][N] fp32 -> WT_hi/lo [Npad][512] bf16 (n-major)
// ---------------------------------------------------------------------------
__global__ __launch_bounds__(256)
void wsplit_k(const float* __restrict__ W, u16* __restrict__ Thi,
              u16* __restrict__ Tlo, int N)
{
    __shared__ float tile[64][68];
    const int tid = threadIdx.x;
    const int n0 = blockIdx.x * 64;
    const int k0 = blockIdx.y * 64;

    #pragma unroll
    for (int it = 0; it < 4; ++it) {
        int idx = it * 256 + tid;
        int kr = idx >> 4;
        int nc = (idx & 15) * 4;
        int n  = n0 + nc;
        float4 v = {0.f, 0.f, 0.f, 0.f};
        const float* wp = W + (size_t)(k0 + kr) * N + n;
        if (n + 3 < N) v = *(const float4*)wp;
        else {
            if (n + 0 < N) v.x = wp[0];
            if (n + 1 < N) v.y = wp[1];
            if (n + 2 < N) v.z = wp[2];
            if (n + 3 < N) v.w = wp[3];
        }
        tile[kr][nc + 0] = v.x; tile[kr][nc + 1] = v.y;
        tile[kr][nc + 2] = v.z; tile[kr][nc + 3] = v.w;
    }
    __syncthreads();

    #pragma unroll
    for (int it = 0; it < 2; ++it) {
        int idx = it * 256 + tid;
        int nr = idx >> 3;
        int kb = (idx & 7) * 8;
        u16x8 hv, lv;
        #pragma unroll
        for (int e = 0; e < 8; ++e) {
            u16 h, l;
            bsplit(tile[kb + e][nr], h, l);
            hv[e] = h; lv[e] = l;
        }
        size_t o = (size_t)(n0 + nr) * 512 + k0 + kb;
        *(u16x8*)(Thi + o) = hv;
        *(u16x8*)(Tlo + o) = lv;
    }
}

// ---------------------------------------------------------------------------
// Gather + split: A[r][:] = emb[tokens], r = t*32+b -> Ahi/Alo [8192][512]
// ---------------------------------------------------------------------------
__global__ __launch_bounds__(256)
void gather_split_k(const int* __restrict__ tokens, const float* __restrict__ emb,
                    u16* __restrict__ Ahi, u16* __restrict__ Alo)
{
    const int r    = blockIdx.x * 4 + (threadIdx.x >> 6);
    const int lane = threadIdx.x & 63;
    const int tok  = tokens[(r & 31) * T_ + (r >> 5)];
    const float* src = emb + (size_t)tok * 512 + lane * 8;
    float4 v0 = *(const float4*)(src);
    float4 v1 = *(const float4*)(src + 4);
    const float vv[8] = {v0.x, v0.y, v0.z, v0.w, v1.x, v1.y, v1.z, v1.w};
    u16x8 hv, lv;
    #pragma unroll
    for (int e = 0; e < 8; ++e) { u16 h, l; bsplit(vv[e], h, l); hv[e] = h; lv[e] = l; }
    size_t o = (size_t)r * 512 + lane * 8;
    *(u16x8*)(Ahi + o) = hv;
    *(u16x8*)(Alo + o) = lv;
}

// ---------------------------------------------------------------------------
// Split-bf16 MFMA GEMM (unchanged; proven)
// ---------------------------------------------------------------------------
template<int MODE>
__global__ __launch_bounds__(256)
void gemm_bf16_k(const u16* __restrict__ Ahi, const u16* __restrict__ Alo,
                 const u16* __restrict__ Bhi, const u16* __restrict__ Blo,
                 const float* __restrict__ bias, float* __restrict__ C, int N)
{
    __shared__ u16 As[2][128 * 64];
    __shared__ u16 Bs[2][128 * 64];

    const int tid  = threadIdx.x;
    const int lane = tid & 63;
    const int wid  = tid >> 6;
    const int wm   = wid >> 1;
    const int wn   = wid & 1;
    const int m0   = blockIdx.y * 128;
    const int n0   = blockIdx.x * 128;

    f32x4 acc[4][4];
    #pragma unroll
    for (int i = 0; i < 4; ++i)
        #pragma unroll
        for (int j = 0; j < 4; ++j) acc[i][j] = (f32x4){0.f, 0.f, 0.f, 0.f};

    auto stage = [&](int s, int buf) {
        const int ksel = s >> 3;
        const int koff = (s & 7) * 64;
        const u16* Asrc = (ksel == 2) ? Alo : Ahi;
        const u16* Bsrc = (ksel == 1) ? Blo : Bhi;
        #pragma unroll
        for (int q = 0; q < 4; ++q) {
            const int u   = q * 256 + tid;
            const int row = u >> 3;
            const int kch = (u & 7) ^ (row & 7);
            const u16* ga = Asrc + (size_t)(m0 + row) * 512 + koff + kch * 8;
            const u16* gb = Bsrc + (size_t)(n0 + row) * 512 + koff + kch * 8;
            u16* la = &As[buf][(q * 256 + wid * 64) * 8];
            u16* lb = &Bs[buf][(q * 256 + wid * 64) * 8];
            __builtin_amdgcn_global_load_lds(
                (const __attribute__((address_space(1))) void*)ga,
                (__attribute__((address_space(3))) void*)la, 16, 0, 0);
            __builtin_amdgcn_global_load_lds(
                (const __attribute__((address_space(1))) void*)gb,
                (__attribute__((address_space(3))) void*)lb, 16, 0, 0);
        }
    };

    stage(0, 0);
    for (int s = 0; s < 24; ++s) {
        const int buf = s & 1;
        __syncthreads();
        if (s + 1 < 24) stage(s + 1, buf ^ 1);

        #pragma unroll
        for (int q = 0; q < 2; ++q) {
            bf16x8 af[4], bfr[4];
            #pragma unroll
            for (int mt = 0; mt < 4; ++mt) {
                const int r    = wm * 64 + mt * 16 + (lane & 15);
                const int slot = (q * 4 + (lane >> 4)) ^ (r & 7);
                af[mt] = *(const bf16x8*)&As[buf][r * 64 + slot * 8];
            }
            #pragma unroll
            for (int nt = 0; nt < 4; ++nt) {
                const int rn   = wn * 64 + nt * 16 + (lane & 15);
                const int slot = (q * 4 + (lane >> 4)) ^ (rn & 7);
                bfr[nt] = *(const bf16x8*)&Bs[buf][rn * 64 + slot * 8];
            }
            #pragma unroll
            for (int mt = 0; mt < 4; ++mt)
                #pragma unroll
                for (int nt = 0; nt < 4; ++nt)
                    acc[mt][nt] = __builtin_amdgcn_mfma_f32_16x16x32_bf16(
                        af[mt], bfr[nt], acc[mt][nt], 0, 0, 0);
        }
    }

    #pragma unroll
    for (int mt = 0; mt < 4; ++mt) {
        #pragma unroll
        for (int nt = 0; nt < 4; ++nt) {
            const int c = n0 + wn * 64 + nt * 16 + (lane & 15);
            #pragma unroll
            for (int j = 0; j < 4; ++j) {
                const int r = m0 + wm * 64 + mt * 16 + (lane >> 4) * 4 + j;
                float val = acc[mt][nt][j];
                if constexpr (MODE == 0) {
                    val += bias[c];
                    const int t = r >> 5, bgrp = (r >> 3) & 3, bb = r & 7;
                    const int g = c >> 9, jblk = (c & 511) >> 3, jjs = c & 7;
                    C[(((size_t)t * 4 + bgrp) * 64 + jblk) * 256 + bb * 32 + g * 8 + jjs] = val;
                } else {
                    if (c < VOC_) {
                        val += bias[c];
                        const size_t orow = (size_t)(r & 31) * T_ + (r >> 5);
                        C[orow * VOC_ + c] = val;
                    }
                }
            }
        }
    }
}

// ---------------------------------------------------------------------------
// 3-role pipelined recurrence, persistent: 768 blocks x 256 thr (3/CU).
//   role A (blk 0..255):   z0 = G[t] + h0@U0 -> h0(t) -> H0x[t+1] (coherent)
//   role B (blk 256..511): G1[t] = h0(t)@W1 + b1  (pure feed-forward)
//   role C (blk 512..767): z1 = G1[t] + h1@U1 -> gates -> h1(t) bf16 out
// r8-identical except: u[] is PINNED to VGPRs via "+v" asm after the load
// (r8: compiler spilled u to scratch -> 5.8 GB refetch, VGPR_Count 76).
// ---------------------------------------------------------------------------
__global__ __launch_bounds__(256, 3)
void rec3_k(const float* __restrict__ G, const float* __restrict__ U0,
            const float* __restrict__ W1, const float* __restrict__ U1,
            const float* __restrict__ b1,
            float* __restrict__ H0x,      // [T+1][32][512], slot0 zeroed
            float* __restrict__ G1,       // [T][4][64][256] swizzled
            u16* __restrict__ Ahi, u16* __restrict__ Alo,
            float* __restrict__ h1buf,    // [2][32][512], slot0 zeroed
            unsigned* __restrict__ bar)
{
    __shared__ float lds[8 * 640];       // [b][chunk kc: 16 floats + 4 pad]

    const int tid  = threadIdx.x;
    const int role = blockIdx.x >> 8;    // 0=A, 1=B, 2=C
    const int blk  = blockIdx.x & 255;
    const int bg   = blk >> 6;
    const int cgr  = blk & 63;
    const int j0   = cgr * 8;
    const int b0   = bg * 8;

    const int jj  = tid >> 5;            // 0..7
    const int kc  = tid & 31;            // 0..31 K-chunk
    const int g_  = kc >> 3;             // final gate
    const int bb_ = kc & 7;              // final batch
    const int gofs = bb_ * 32 + g_ * 8 + jj;

    // barrier regions: per (role,bg), 4 shards (16 blocks each) + 1 root
    unsigned* baseA = bar + (0 * 4 + bg) * 80;
    unsigned* baseB = bar + (1 * 4 + bg) * 80;
    unsigned* baseC = bar + (2 * 4 + bg) * 80;
    unsigned* mybase  = (role == 0) ? baseA : (role == 1) ? baseB : baseC;
    unsigned* myshard = mybase + (cgr & 3) * 16;
    unsigned* myroot  = mybase + 64;
    unsigned* rootA = baseA + 64;
    unsigned* rootB = baseB + 64;
    unsigned* rootC = baseC + 64;

    // persistent weights, DIRECT layout (r6-proven): u[g] = gate g
    const float* Usrc = (role == 0) ? U0 : (role == 1) ? W1 : U1;
    float u[4][16];
    #pragma unroll
    for (int g = 0; g < 4; ++g)
        #pragma unroll
        for (int kk = 0; kk < 16; ++kk)
            u[g][kk] = Usrc[(size_t)(kc * 16 + kk) * G4_ + (g << 9) + j0 + jj];

    // PIN u in VGPRs: "+v" makes each element's definition opaque, so the
    // compiler can neither rematerialize the global load inside the t-loop
    // nor treat it as cheaply-spillable loop-invariant code. (r8 fix)
    #pragma unroll
    for (int g = 0; g < 4; ++g)
        #pragma unroll
        for (int kk = 0; kk < 16; ++kk)
            asm volatile("" : "+v"(u[g][kk]));

    // r6-verbatim per-step compute: stage(src)->lds, dots, butterfly -> z
    auto stage_tile = [&](const float* src) {
        const float* p[4]; float* dst[4];
        #pragma unroll
        for (int q = 0; q < 4; ++q) {
            int idx = q * 256 + tid;
            int bL  = idx >> 7;
            int k4  = idx & 127;
            p[q]   = src + (b0 + bL) * HID_ + k4 * 4;
            dst[q] = &lds[bL * 640 + (k4 >> 2) * 20 + (k4 & 3) * 4];
        }
        f32x4 v0, v1, v2, v3;
        load4_coherent(p[0], p[1], p[2], p[3], v0, v1, v2, v3);
        *(f32x4*)dst[0] = v0; *(f32x4*)dst[1] = v1;
        *(f32x4*)dst[2] = v2; *(f32x4*)dst[3] = v3;
    };

    auto dot_reduce = [&]() -> float {
        float v[32];
        #pragma unroll
        for (int s = 0; s < 32; ++s) v[s] = 0.f;
        #pragma unroll
        for (int bb = 0; bb < 8; ++bb) {
            const float* hp = &lds[bb * 640 + kc * 20];
            f32x4 h0v = *(const f32x4*)(hp + 0);
            f32x4 h1v = *(const f32x4*)(hp + 4);
            f32x4 h2v = *(const f32x4*)(hp + 8);
            f32x4 h3v = *(const f32x4*)(hp + 12);
            const float hh[16] = {h0v.x, h0v.y, h0v.z, h0v.w, h1v.x, h1v.y, h1v.z, h1v.w,
                                  h2v.x, h2v.y, h2v.z, h2v.w, h3v.x, h3v.y, h3v.z, h3v.w};
            #pragma unroll
            for (int g = 0; g < 4; ++g)
                #pragma unroll
                for (int kk = 0; kk < 16; ++kk)
                    v[g * 8 + bb] += u[g][kk] * hh[kk];
        }
        float a16[16];
        #pragma unroll
        for (int i = 0; i < 16; ++i) {
            float keep = (kc & 16) ? v[i + 16] : v[i];
            float give = (kc & 16) ? v[i]      : v[i + 16];
            a16[i] = keep + __shfl_xor(give, 16, 32);
        }
        float a8[8];
        #pragma unroll
        for (int i = 0; i < 8; ++i) {
            float keep = (kc & 8) ? a16[i + 8] : a16[i];
            float give = (kc & 8) ? a16[i]     : a16[i + 8];
            a8[i] = keep + __shfl_xor(give, 8, 32);
        }
        float a4[4];
        #pragma unroll
        for (int i = 0; i < 4; ++i) {
            float keep = (kc & 4) ? a8[i + 4] : a8[i];
            float give = (kc & 4) ? a8[i]     : a8[i + 4];
            a4[i] = keep + __shfl_xor(give, 4, 32);
        }
        float a2[2];
        #pragma unroll
        for (int i = 0; i < 2; ++i) {
            float keep = (kc & 2) ? a4[i + 2] : a4[i];
            float give = (kc & 2) ? a4[i]     : a4[i + 2];
            a2[i] = keep + __shfl_xor(give, 2, 32);
        }
        float keep1 = (kc & 1) ? a2[1] : a2[0];
        float give1 = (kc & 1) ? a2[0] : a2[1];
        return keep1 + __shfl_xor(give1, 1, 32);
    };

    auto arrive = [&](int t) {
        if (tid == 0) {
            unsigned old = AADD(myshard);
            if (old + 1u == 16u * (unsigned)(t + 1)) AADD(myroot);
        }
    };

    if (role == 0) {
        // ---------------- ROLE A: layer-0 recurrence ----------------
        float zpre = G[((size_t)bg * 64 + cgr) * 256 + gofs];
        float c_reg = 0.f;
        for (int t = 0; t < T_; ++t) {
            if (tid == 0 && t > 0) wait_ge(rootA, 4u * (unsigned)t);
            __syncthreads();
            stage_tile(H0x + (size_t)t * BH_);
            __syncthreads();

            float zpn = 0.f;
            if (t + 1 < T_)
                zpn = G[(((size_t)(t + 1) * 4 + bg) * 64 + cgr) * 256 + gofs];

            float z = dot_reduce() + zpre;
            zpre = zpn;

            float z8  = __shfl_xor(z, 8, 32);
            float z16 = __shfl_xor(z, 16, 32);
            float z24 = __shfl_xor(z, 24, 32);
            float i_ = fsigm(z);
            float f_ = fsigm(z8);
            float gg = ftanh(z16);
            float o_ = fsigm(z24);
            c_reg = f_ * c_reg + i_ * gg;
            float h_ = o_ * ftanh(c_reg);

            if (g_ == 0)
                store_coherent(&H0x[(size_t)(t + 1) * BH_ + (b0 + bb_) * HID_ + j0 + jj], h_);

            __syncthreads();          // drain stores before arrival
            arrive(t);
        }
    } else if (role == 1) {
        // ---------------- ROLE B: G1[t] = h0(t) @ W1 + b1 ----------------
        const float zb = b1[(g_ << 9) + j0 + jj];
        for (int t = 0; t < T_; ++t) {
            if (tid == 0) wait_ge(rootA, 4u * (unsigned)(t + 1));
            __syncthreads();
            stage_tile(H0x + (size_t)(t + 1) * BH_);
            __syncthreads();

            float z = dot_reduce() + zb;
            store_coherent(&G1[(((size_t)t * 4 + bg) * 64 + cgr) * 256 + gofs], z);

            __syncthreads();
            arrive(t);
        }
    } else {
        // ---------------- ROLE C: layer-1 recurrence ----------------
        float c_reg = 0.f;
        for (int t = 0; t < T_; ++t) {
            if (tid == 0) {
                wait_ge(rootB, 4u * (unsigned)(t + 1));          // G1[t] ready
                if (t > 0) wait_ge(rootC, 4u * (unsigned)t);     // h1(t-1) ready
            }
            __syncthreads();
            stage_tile(h1buf + (size_t)(t & 1) * BH_);
            float g1v = load_coherent_f32(
                G1 + (((size_t)t * 4 + bg) * 64 + cgr) * 256 + gofs);
            __syncthreads();

            float z = dot_reduce() + g1v;

            float z8  = __shfl_xor(z, 8, 32);
            float z16 = __shfl_xor(z, 16, 32);
            float z24 = __shfl_xor(z, 24, 32);
            float i_ = fsigm(z);
            float f_ = fsigm(z8);
            float gg = ftanh(z16);
            float o_ = fsigm(z24);
            c_reg = f_ * c_reg + i_ * gg;
            float h_ = o_ * ftanh(c_reg);

            if (g_ == 0) {
                const int brow = b0 + bb_;
                store_coherent(&h1buf[(size_t)((t + 1) & 1) * BH_ + brow * HID_ + j0 + jj], h_);
                u16 hi, lo; bsplit(h_, hi, lo);
                const size_t o = ((size_t)t * B_ + brow) * HID_ + j0 + jj;
                Ahi[o] = hi;                   // cached; next kernel consumes
                Alo[o] = lo;
            }

            __syncthreads();
            arrive(t);
        }
    }
}

// ---------------------------------------------------------------------------
extern "C" void kernel_launch(void* const* d_in, const int* in_sizes, int n_in,
                              void* d_out, int out_size, void* d_ws, size_t ws_size,
                              hipStream_t stream)
{
    const int*   tokens = (const int*)  d_in[0];
    const float* emb    = (const float*)d_in[1];
    const float* W0     = (const float*)d_in[2];
    const float* U0     = (const float*)d_in[3];
    const float* b0     = (const float*)d_in[4];
    const float* W1     = (const float*)d_in[5];
    const float* U1     = (const float*)d_in[6];
    const float* b1     = (const float*)d_in[7];
    const float* Wout   = (const float*)d_in[8];
    const float* bout   = (const float*)d_in[9];
    float* out = (float*)d_out;

    // d_out scratch (all dead before the final GEMM overwrites d_out):
    //   G [16.78M fp32] | H0x [257*32*512 = 4.21M] | G1 [16.78M]
    float* G   = out;
    float* H0x = out + (size_t)8192 * 2048;
    float* G1  = H0x + (size_t)(T_ + 1) * BH_;

    u16* ws16 = (u16*)d_ws;
    size_t o = 0;
    u16* Ahi   = ws16 + o; o += (size_t)8192 * 512;
    u16* Alo   = ws16 + o; o += (size_t)8192 * 512;
    u16* W0Thi = ws16 + o; o += (size_t)G4_ * 512;
    u16* W0Tlo = ws16 + o; o += (size_t)G4_ * 512;
    u16* WoThi = ws16 + o; o += (size_t)NPAD_ * 512;
    u16* WoTlo = ws16 + o; o += (size_t)NPAD_ * 512;
    float*    h1buf = (float*)(ws16 + o);
    unsigned* bar   = (unsigned*)(h1buf + 2 * BH_);

    dim3 blk(256);

    // prep: weight transpose+split (W0, Wout) and embedding gather+split
    wsplit_k<<<dim3(G4_ / 64, 8), blk, 0, stream>>>(W0, W0Thi, W0Tlo, G4_);
    wsplit_k<<<dim3(NPAD_ / 64, 8), blk, 0, stream>>>(Wout, WoThi, WoTlo, VOC_);
    gather_split_k<<<dim3(2048), blk, 0, stream>>>(tokens, emb, Ahi, Alo);

    // G = X0 @ W0 + b0   (split-bf16 MFMA, recurrence-swizzled store)
    gemm_bf16_k<0><<<dim3(G4_ / 128, 64), blk, 0, stream>>>(
        Ahi, Alo, W0Thi, W0Tlo, b0, G, G4_);

    // 3-role pipelined recurrence -> Ahi/Alo (h1 bf16)
    hipMemsetAsync(H0x, 0, BH_ * sizeof(float), stream);     // h0(0) = 0
    hipMemsetAsync(h1buf, 0, BH_ * sizeof(float), stream);   // h1(0) = 0
    hipMemsetAsync(bar, 0, 1024 * sizeof(unsigned), stream); // barriers
    rec3_k<<<dim3(768), blk, 0, stream>>>(
        G, U0, W1, U1, b1, H0x, G1, Ahi, Alo, h1buf, bar);

    // out[b*T+t, :] = H1 @ W_out + b_out
    gemm_bf16_k<1><<<dim3(NPAD_ / 128, 64), blk, 0, stream>>>(
        Ahi, Alo, WoThi, WoTlo, bout, out, NPAD_);
}

// Round 11
// 2215.409 us; speedup vs baseline: 1.6260x; 1.6260x over previous
//
#include <hip/hip_runtime.h>
#include <math.h>

#define B_    32
#define T_    256
#define HID_  512
#define G4_   2048   // 4*HID
#define VOC_  10000
#define NPAD_ 10112  // 79*128, padded vocab for the bf16 GEMM

typedef float f32x4 __attribute__((ext_vector_type(4)));
typedef short bf16x8 __attribute__((ext_vector_type(8)));
typedef unsigned short u16;
typedef u16 u16x8 __attribute__((ext_vector_type(8)));

#define AADD(p)  __hip_atomic_fetch_add((p), 1u, __ATOMIC_RELAXED, __HIP_MEMORY_SCOPE_AGENT)
#define ALOAD(p) __hip_atomic_load((p), __ATOMIC_RELAXED, __HIP_MEMORY_SCOPE_AGENT)

// ---------------- coherent (cross-XCD via IF$) helpers: sc0 sc1 ------------
__device__ __forceinline__ void load4_coherent(const float* p0, const float* p1,
                                               const float* p2, const float* p3,
                                               f32x4& a, f32x4& b, f32x4& c, f32x4& d)
{
    asm volatile(
        "global_load_dwordx4 %0, %4, off sc0 sc1\n\t"
        "global_load_dwordx4 %1, %5, off sc0 sc1\n\t"
        "global_load_dwordx4 %2, %6, off sc0 sc1\n\t"
        "global_load_dwordx4 %3, %7, off sc0 sc1\n\t"
        "s_waitcnt vmcnt(0)"
        : "=&v"(a), "=&v"(b), "=&v"(c), "=&v"(d)
        : "v"(p0), "v"(p1), "v"(p2), "v"(p3)
        : "memory");
}
__device__ __forceinline__ void store_coherent(float* p, float x)
{
    asm volatile("global_store_dword %0, %1, off sc0 sc1" :: "v"(p), "v"(x) : "memory");
}

__device__ __forceinline__ float fsigm(float x)
{
    float e = exp2f(x * -1.4426950408889634f);
    return __builtin_amdgcn_rcpf(1.f + e);
}
__device__ __forceinline__ float ftanh(float x)
{
    float e = exp2f(x * 2.8853900817779268f);
    return 1.f - 2.f * __builtin_amdgcn_rcpf(e + 1.f);
}

// fp32 -> bf16_hi + bf16_lo (RNE both; a ~= hi + lo with ~16 mantissa bits)
__device__ __forceinline__ void bsplit(float x, u16& hi, u16& lo)
{
    union { float f; unsigned u; } a; a.f = x;
    unsigned r = a.u + 0x7FFFu + ((a.u >> 16) & 1u);
    hi = (u16)(r >> 16);
    union { unsigned u; float f; } hf; hf.u = ((unsigned)hi) << 16;
    union { float f; unsigned u; } b; b.f = x - hf.f;
    unsigned r2 = b.u + 0x7FFFu + ((b.u >> 16) & 1u);
    lo = (u16)(r2 >> 16);
}

// spin until *p >= tgt (monotonic counter), with hang-safety bail
__device__ __forceinline__ void wait_ge(unsigned* p, unsigned tgt)
{
    unsigned g = 0;
    while (ALOAD(p) < tgt) {
        __builtin_amdgcn_s_sleep(2);
        if (++g > 100000000u) break;
    }
}

// ---------------------------------------------------------------------------
// Transpose + split: W [512][N] fp32 -> WT_hi/lo [Npad][512] bf16 (n-major)
// ---------------------------------------------------------------------------
__global__ __launch_bounds__(256)
void wsplit_k(const float* __restrict__ W, u16* __restrict__ Thi,
              u16* __restrict__ Tlo, int N)
{
    __shared__ float tile[64][68];
    const int tid = threadIdx.x;
    const int n0 = blockIdx.x * 64;
    const int k0 = blockIdx.y * 64;

    #pragma unroll
    for (int it = 0; it < 4; ++it) {
        int idx = it * 256 + tid;
        int kr = idx >> 4;
        int nc = (idx & 15) * 4;
        int n  = n0 + nc;
        float4 v = {0.f, 0.f, 0.f, 0.f};
        const float* wp = W + (size_t)(k0 + kr) * N + n;
        if (n + 3 < N) v = *(const float4*)wp;
        else {
            if (n + 0 < N) v.x = wp[0];
            if (n + 1 < N) v.y = wp[1];
            if (n + 2 < N) v.z = wp[2];
            if (n + 3 < N) v.w = wp[3];
        }
        tile[kr][nc + 0] = v.x; tile[kr][nc + 1] = v.y;
        tile[kr][nc + 2] = v.z; tile[kr][nc + 3] = v.w;
    }
    __syncthreads();

    #pragma unroll
    for (int it = 0; it < 2; ++it) {
        int idx = it * 256 + tid;
        int nr = idx >> 3;
        int kb = (idx & 7) * 8;
        u16x8 hv, lv;
        #pragma unroll
        for (int e = 0; e < 8; ++e) {
            u16 h, l;
            bsplit(tile[kb + e][nr], h, l);
            hv[e] = h; lv[e] = l;
        }
        size_t o = (size_t)(n0 + nr) * 512 + k0 + kb;
        *(u16x8*)(Thi + o) = hv;
        *(u16x8*)(Tlo + o) = lv;
    }
}

// ---------------------------------------------------------------------------
// Gather + split: A[r][:] = emb[tokens], r = t*32+b -> Ahi/Alo [8192][512]
// ---------------------------------------------------------------------------
__global__ __launch_bounds__(256)
void gather_split_k(const int* __restrict__ tokens, const float* __restrict__ emb,
                    u16* __restrict__ Ahi, u16* __restrict__ Alo)
{
    const int r    = blockIdx.x * 4 + (threadIdx.x >> 6);
    const int lane = threadIdx.x & 63;
    const int tok  = tokens[(r & 31) * T_ + (r >> 5)];
    const float* src = emb + (size_t)tok * 512 + lane * 8;
    float4 v0 = *(const float4*)(src);
    float4 v1 = *(const float4*)(src + 4);
    const float vv[8] = {v0.x, v0.y, v0.z, v0.w, v1.x, v1.y, v1.z, v1.w};
    u16x8 hv, lv;
    #pragma unroll
    for (int e = 0; e < 8; ++e) { u16 h, l; bsplit(vv[e], h, l); hv[e] = h; lv[e] = l; }
    size_t o = (size_t)r * 512 + lane * 8;
    *(u16x8*)(Ahi + o) = hv;
    *(u16x8*)(Alo + o) = lv;
}

// ---------------------------------------------------------------------------
// Split-bf16 MFMA GEMM (unchanged from round 5/6; proven)
// ---------------------------------------------------------------------------
template<int MODE>
__global__ __launch_bounds__(256)
void gemm_bf16_k(const u16* __restrict__ Ahi, const u16* __restrict__ Alo,
                 const u16* __restrict__ Bhi, const u16* __restrict__ Blo,
                 const float* __restrict__ bias, float* __restrict__ C, int N)
{
    __shared__ u16 As[2][128 * 64];
    __shared__ u16 Bs[2][128 * 64];

    const int tid  = threadIdx.x;
    const int lane = tid & 63;
    const int wid  = tid >> 6;
    const int wm   = wid >> 1;
    const int wn   = wid & 1;
    const int m0   = blockIdx.y * 128;
    const int n0   = blockIdx.x * 128;

    f32x4 acc[4][4];
    #pragma unroll
    for (int i = 0; i < 4; ++i)
        #pragma unroll
        for (int j = 0; j < 4; ++j) acc[i][j] = (f32x4){0.f, 0.f, 0.f, 0.f};

    auto stage = [&](int s, int buf) {
        const int ksel = s >> 3;
        const int koff = (s & 7) * 64;
        const u16* Asrc = (ksel == 2) ? Alo : Ahi;
        const u16* Bsrc = (ksel == 1) ? Blo : Bhi;
        #pragma unroll
        for (int q = 0; q < 4; ++q) {
            const int u   = q * 256 + tid;
            const int row = u >> 3;
            const int kch = (u & 7) ^ (row & 7);
            const u16* ga = Asrc + (size_t)(m0 + row) * 512 + koff + kch * 8;
            const u16* gb = Bsrc + (size_t)(n0 + row) * 512 + koff + kch * 8;
            u16* la = &As[buf][(q * 256 + wid * 64) * 8];
            u16* lb = &Bs[buf][(q * 256 + wid * 64) * 8];
            __builtin_amdgcn_global_load_lds(
                (const __attribute__((address_space(1))) void*)ga,
                (__attribute__((address_space(3))) void*)la, 16, 0, 0);
            __builtin_amdgcn_global_load_lds(
                (const __attribute__((address_space(1))) void*)gb,
                (__attribute__((address_space(3))) void*)lb, 16, 0, 0);
        }
    };

    stage(0, 0);
    for (int s = 0; s < 24; ++s) {
        const int buf = s & 1;
        __syncthreads();
        if (s + 1 < 24) stage(s + 1, buf ^ 1);

        #pragma unroll
        for (int q = 0; q < 2; ++q) {
            bf16x8 af[4], bfr[4];
            #pragma unroll
            for (int mt = 0; mt < 4; ++mt) {
                const int r    = wm * 64 + mt * 16 + (lane & 15);
                const int slot = (q * 4 + (lane >> 4)) ^ (r & 7);
                af[mt] = *(const bf16x8*)&As[buf][r * 64 + slot * 8];
            }
            #pragma unroll
            for (int nt = 0; nt < 4; ++nt) {
                const int rn   = wn * 64 + nt * 16 + (lane & 15);
                const int slot = (q * 4 + (lane >> 4)) ^ (rn & 7);
                bfr[nt] = *(const bf16x8*)&Bs[buf][rn * 64 + slot * 8];
            }
            #pragma unroll
            for (int mt = 0; mt < 4; ++mt)
                #pragma unroll
                for (int nt = 0; nt < 4; ++nt)
                    acc[mt][nt] = __builtin_amdgcn_mfma_f32_16x16x32_bf16(
                        af[mt], bfr[nt], acc[mt][nt], 0, 0, 0);
        }
    }

    #pragma unroll
    for (int mt = 0; mt < 4; ++mt) {
        #pragma unroll
        for (int nt = 0; nt < 4; ++nt) {
            const int c = n0 + wn * 64 + nt * 16 + (lane & 15);
            #pragma unroll
            for (int j = 0; j < 4; ++j) {
                const int r = m0 + wm * 64 + mt * 16 + (lane >> 4) * 4 + j;
                float val = acc[mt][nt][j];
                if constexpr (MODE == 0) {
                    val += bias[c];
                    const int t = r >> 5, bgrp = (r >> 3) & 3, bb = r & 7;
                    const int g = c >> 9, jblk = (c & 511) >> 3, jjs = c & 7;
                    C[(((size_t)t * 4 + bgrp) * 64 + jblk) * 256 + bb * 32 + g * 8 + jjs] = val;
                } else {
                    if (c < VOC_) {
                        val += bias[c];
                        const size_t orow = (size_t)(r & 31) * T_ + (r >> 5);
                        C[orow * VOC_ + c] = val;
                    }
                }
            }
        }
    }
}

// ---------------------------------------------------------------------------
// FUSED 2-layer LSTM recurrence, persistent: 512 blocks x 256 thr.
// r6-verbatim (passed, 2215us total) EXCEPT __launch_bounds__(256, 1):
// register-allocator evidence across r3/r6/r8/r9 shows hipcc keeps persistent
// weight arrays in VGPRs ONLY at min-waves=1 (r3: 128 floats -> VGPR 180, no
// spill); any >=2 declaration spills them to scratch (r6: VGPR 104, r8: 76,
// 5.8 GB scratch refetch). HW still co-schedules 2 blocks/CU when VGPR<=256.
// Blocks 0..255   = LAYER 0; blocks 256..511 = LAYER 1 (concatenated K=1024).
// Layer 0 never waits on layer 1 => deadlock-free at ANY residency (if only
// 1 block/CU fits, layer 1 runs after layer 0 retires -- slower, not wrong).
// ---------------------------------------------------------------------------
__global__ __launch_bounds__(256, 1)
void fused_rec_k(const float* __restrict__ G, const float* __restrict__ U0,
                 const float* __restrict__ W1, const float* __restrict__ U1,
                 const float* __restrict__ b1,
                 float* __restrict__ H0x,      // [T+1][32][512], slot0 zeroed
                 u16* __restrict__ Ahi, u16* __restrict__ Alo,
                 float* __restrict__ h1buf,    // [2][32][512], slot0 zeroed
                 unsigned* __restrict__ bar)
{
    __shared__ float lds[8 * 1152];      // L0 uses [8][640]; L1 uses [8][32][36]

    const int tid  = threadIdx.x;
    const int role = blockIdx.x >> 8;    // 0 = layer0, 1 = layer1
    const int blk  = blockIdx.x & 255;
    const int bg   = blk >> 6;           // 0..3  batch group
    const int cgr  = blk & 63;           // 0..63 column group
    const int j0   = cgr * 8;
    const int b0   = bg * 8;

    const int jj  = tid >> 5;            // 0..7
    const int kc  = tid & 31;            // 0..31 K-chunk
    const int g_  = kc >> 3;             // gate after reduce-scatter
    const int bb_ = kc & 7;              // batch after reduce-scatter
    const int shard = cgr & 3;

    // barrier pointers: shards 64B apart, roots separate
    unsigned* shard0 = bar + (bg * 4 + shard) * 16;
    unsigned* root0  = bar + 256 + bg * 16;
    unsigned* shard1 = bar + 512 + (bg * 4 + shard) * 16;
    unsigned* root1  = bar + 768 + bg * 16;

    if (role == 0) {
        // ---------------- LAYER 0 ----------------
        float u[4][16];
        #pragma unroll
        for (int g = 0; g < 4; ++g)
            #pragma unroll
            for (int kk = 0; kk < 16; ++kk)
                u[g][kk] = U0[(size_t)(kc * 16 + kk) * G4_ + (g << 9) + j0 + jj];

        const int gofs = bb_ * 32 + g_ * 8 + jj;
        float zpre = G[((size_t)bg * 64 + cgr) * 256 + gofs];
        float c_reg = 0.f;

        for (int t = 0; t < T_; ++t) {
            if (tid == 0 && t > 0) wait_ge(root0, 4u * (unsigned)t);
            __syncthreads();                       // SYNC_A: h0(t) ready, lds free

            // stage h0(t)=H0x[t] [8][512] -> lds (stride-20 padded)
            {
                const float* p[4]; float* dst[4];
                const float* hcur = H0x + (size_t)t * (B_ * HID_);
                #pragma unroll
                for (int q = 0; q < 4; ++q) {
                    int idx = q * 256 + tid;
                    int bL  = idx >> 7;
                    int k4  = idx & 127;
                    p[q]   = hcur + (b0 + bL) * HID_ + k4 * 4;
                    dst[q] = &lds[bL * 640 + (k4 >> 2) * 20 + (k4 & 3) * 4];
                }
                f32x4 v0, v1, v2, v3;
                load4_coherent(p[0], p[1], p[2], p[3], v0, v1, v2, v3);
                *(f32x4*)dst[0] = v0; *(f32x4*)dst[1] = v1;
                *(f32x4*)dst[2] = v2; *(f32x4*)dst[3] = v3;
            }
            __syncthreads();                       // SYNC_B

            float zpre_next = 0.f;
            if (t + 1 < T_)
                zpre_next = G[((size_t)((t + 1) * 4 + bg) * 64 + cgr) * 256 + gofs];

            float v[32];
            #pragma unroll
            for (int s = 0; s < 32; ++s) v[s] = 0.f;
            #pragma unroll
            for (int bb = 0; bb < 8; ++bb) {
                const float* hp = &lds[bb * 640 + kc * 20];
                f32x4 h0v = *(const f32x4*)(hp + 0);
                f32x4 h1v = *(const f32x4*)(hp + 4);
                f32x4 h2v = *(const f32x4*)(hp + 8);
                f32x4 h3v = *(const f32x4*)(hp + 12);
                const float hh[16] = {h0v.x, h0v.y, h0v.z, h0v.w, h1v.x, h1v.y, h1v.z, h1v.w,
                                      h2v.x, h2v.y, h2v.z, h2v.w, h3v.x, h3v.y, h3v.z, h3v.w};
                #pragma unroll
                for (int g = 0; g < 4; ++g)
                    #pragma unroll
                    for (int kk = 0; kk < 16; ++kk)
                        v[g * 8 + bb] += u[g][kk] * hh[kk];
            }

            // reduce-scatter over 32 kc lanes
            float a16[16];
            #pragma unroll
            for (int i = 0; i < 16; ++i) {
                float keep = (kc & 16) ? v[i + 16] : v[i];
                float give = (kc & 16) ? v[i]      : v[i + 16];
                a16[i] = keep + __shfl_xor(give, 16, 32);
            }
            float a8[8];
            #pragma unroll
            for (int i = 0; i < 8; ++i) {
                float keep = (kc & 8) ? a16[i + 8] : a16[i];
                float give = (kc & 8) ? a16[i]     : a16[i + 8];
                a8[i] = keep + __shfl_xor(give, 8, 32);
            }
            float a4[4];
            #pragma unroll
            for (int i = 0; i < 4; ++i) {
                float keep = (kc & 4) ? a8[i + 4] : a8[i];
                float give = (kc & 4) ? a8[i]     : a8[i + 4];
                a4[i] = keep + __shfl_xor(give, 4, 32);
            }
            float a2[2];
            #pragma unroll
            for (int i = 0; i < 2; ++i) {
                float keep = (kc & 2) ? a4[i + 2] : a4[i];
                float give = (kc & 2) ? a4[i]     : a4[i + 2];
                a2[i] = keep + __shfl_xor(give, 2, 32);
            }
            float keep1 = (kc & 1) ? a2[1] : a2[0];
            float give1 = (kc & 1) ? a2[0] : a2[1];
            float z = keep1 + __shfl_xor(give1, 1, 32) + zpre;
            zpre = zpre_next;

            float z8  = __shfl_xor(z, 8, 32);
            float z16 = __shfl_xor(z, 16, 32);
            float z24 = __shfl_xor(z, 24, 32);
            float i_ = fsigm(z);
            float f_ = fsigm(z8);
            float gg = ftanh(z16);
            float o_ = fsigm(z24);
            c_reg = f_ * c_reg + i_ * gg;
            float h_ = o_ * ftanh(c_reg);

            if (g_ == 0)
                store_coherent(&H0x[(size_t)(t + 1) * (B_ * HID_)
                                    + (b0 + bb_) * HID_ + j0 + jj], h_);

            __syncthreads();                       // SYNC_C: stores drained
            if (tid == 0) {
                unsigned old = AADD(shard0);
                if (old + 1u == 16u * (unsigned)(t + 1)) AADD(root0);
            }
        }
    } else {
        // ---------------- LAYER 1 ----------------
        // concatenated K=1024: kc<16 -> W1 rows (x part), kc>=16 -> U1 (h part)
        float u[4][32];
        #pragma unroll
        for (int g = 0; g < 4; ++g)
            #pragma unroll
            for (int kk = 0; kk < 32; ++kk) {
                const int K = kc * 32 + kk;
                u[g][kk] = (K < 512)
                    ? W1[(size_t)K * G4_ + (g << 9) + j0 + jj]
                    : U1[(size_t)(K - 512) * G4_ + (g << 9) + j0 + jj];
            }
        const float zb = b1[(g_ << 9) + j0 + jj];
        float c_reg = 0.f;

        for (int t = 0; t < T_; ++t) {
            if (tid == 0) {
                wait_ge(root0, 4u * (unsigned)(t + 1));          // h0(t) ready
                if (t > 0) wait_ge(root1, 4u * (unsigned)t);     // h1(t) ready
            }
            __syncthreads();                       // SYNC_A

            // stage [x=h0(t) | h1(t)] [8][1024] -> lds[b][kc][36]
            {
                const float* xbase = H0x  + (size_t)(t + 1) * (B_ * HID_);
                const float* hbase = h1buf + (size_t)(t & 1) * (B_ * HID_);
                const float* p[8]; float* dst[8];
                const int k = tid * 4;             // 0..1020
                #pragma unroll
                for (int q = 0; q < 8; ++q) {
                    p[q] = (k < 512) ? (xbase + (b0 + q) * HID_ + k)
                                     : (hbase + (b0 + q) * HID_ + (k - 512));
                    dst[q] = &lds[q * 1152 + (tid >> 3) * 36 + (tid & 7) * 4];
                }
                f32x4 v0, v1, v2, v3, v4, v5, v6, v7;
                load4_coherent(p[0], p[1], p[2], p[3], v0, v1, v2, v3);
                load4_coherent(p[4], p[5], p[6], p[7], v4, v5, v6, v7);
                *(f32x4*)dst[0] = v0; *(f32x4*)dst[1] = v1;
                *(f32x4*)dst[2] = v2; *(f32x4*)dst[3] = v3;
                *(f32x4*)dst[4] = v4; *(f32x4*)dst[5] = v5;
                *(f32x4*)dst[6] = v6; *(f32x4*)dst[7] = v7;
            }
            __syncthreads();                       // SYNC_B

            float v[32];
            #pragma unroll
            for (int s = 0; s < 32; ++s) v[s] = 0.f;
            #pragma unroll
            for (int bb = 0; bb < 8; ++bb) {
                const float* hp = &lds[bb * 1152 + kc * 36];
                #pragma unroll
                for (int half = 0; half < 2; ++half) {
                    f32x4 h0v = *(const f32x4*)(hp + half * 16 + 0);
                    f32x4 h1v = *(const f32x4*)(hp + half * 16 + 4);
                    f32x4 h2v = *(const f32x4*)(hp + half * 16 + 8);
                    f32x4 h3v = *(const f32x4*)(hp + half * 16 + 12);
                    const float hh[16] = {h0v.x, h0v.y, h0v.z, h0v.w, h1v.x, h1v.y, h1v.z, h1v.w,
                                          h2v.x, h2v.y, h2v.z, h2v.w, h3v.x, h3v.y, h3v.z, h3v.w};
                    #pragma unroll
                    for (int g = 0; g < 4; ++g)
                        #pragma unroll
                        for (int kk = 0; kk < 16; ++kk)
                            v[g * 8 + bb] += u[g][half * 16 + kk] * hh[kk];
                }
            }

            float a16[16];
            #pragma unroll
            for (int i = 0; i < 16; ++i) {
                float keep = (kc & 16) ? v[i + 16] : v[i];
                float give = (kc & 16) ? v[i]      : v[i + 16];
                a16[i] = keep + __shfl_xor(give, 16, 32);
            }
            float a8[8];
            #pragma unroll
            for (int i = 0; i < 8; ++i) {
                float keep = (kc & 8) ? a16[i + 8] : a16[i];
                float give = (kc & 8) ? a16[i]     : a16[i + 8];
                a8[i] = keep + __shfl_xor(give, 8, 32);
            }
            float a4[4];
            #pragma unroll
            for (int i = 0; i < 4; ++i) {
                float keep = (kc & 4) ? a8[i + 4] : a8[i];
                float give = (kc & 4) ? a8[i]     : a8[i + 4];
                a4[i] = keep + __shfl_xor(give, 4, 32);
            }
            float a2[2];
            #pragma unroll
            for (int i = 0; i < 2; ++i) {
                float keep = (kc & 2) ? a4[i + 2] : a4[i];
                float give = (kc & 2) ? a4[i]     : a4[i + 2];
                a2[i] = keep + __shfl_xor(give, 2, 32);
            }
            float keep1 = (kc & 1) ? a2[1] : a2[0];
            float give1 = (kc & 1) ? a2[0] : a2[1];
            float z = keep1 + __shfl_xor(give1, 1, 32) + zb;

            float z8  = __shfl_xor(z, 8, 32);
            float z16 = __shfl_xor(z, 16, 32);
            float z24 = __shfl_xor(z, 24, 32);
            float i_ = fsigm(z);
            float f_ = fsigm(z8);
            float gg = ftanh(z16);
            float o_ = fsigm(z24);
            c_reg = f_ * c_reg + i_ * gg;
            float h_ = o_ * ftanh(c_reg);

            if (g_ == 0) {
                const int brow = b0 + bb_;
                store_coherent(&h1buf[(size_t)((t + 1) & 1) * (B_ * HID_)
                                      + brow * HID_ + j0 + jj], h_);
                u16 hi, lo; bsplit(h_, hi, lo);
                const size_t o = ((size_t)t * B_ + brow) * HID_ + j0 + jj;
                Ahi[o] = hi;
                Alo[o] = lo;
            }

            __syncthreads();                       // SYNC_C: stores drained
            if (tid == 0) {
                unsigned old = AADD(shard1);
                if (old + 1u == 16u * (unsigned)(t + 1)) AADD(root1);
            }
        }
    }
}

// ---------------------------------------------------------------------------
extern "C" void kernel_launch(void* const* d_in, const int* in_sizes, int n_in,
                              void* d_out, int out_size, void* d_ws, size_t ws_size,
                              hipStream_t stream)
{
    const int*   tokens = (const int*)  d_in[0];
    const float* emb    = (const float*)d_in[1];
    const float* W0     = (const float*)d_in[2];
    const float* U0     = (const float*)d_in[3];
    const float* b0     = (const float*)d_in[4];
    const float* W1     = (const float*)d_in[5];
    const float* U1     = (const float*)d_in[6];
    const float* b1     = (const float*)d_in[7];
    const float* Wout   = (const float*)d_in[8];
    const float* bout   = (const float*)d_in[9];
    float* out = (float*)d_out;

    // d_out scratch: G (8192x2048 fp32 swizzled) then H0x ([T+1][32][512]) --
    // both dead before the final GEMM overwrites all of d_out.
    float* G   = out;
    float* H0x = out + (size_t)8192 * 2048;

    u16* ws16 = (u16*)d_ws;
    size_t o = 0;
    u16* Ahi   = ws16 + o; o += (size_t)8192 * 512;
    u16* Alo   = ws16 + o; o += (size_t)8192 * 512;
    u16* W0Thi = ws16 + o; o += (size_t)G4_ * 512;
    u16* W0Tlo = ws16 + o; o += (size_t)G4_ * 512;
    u16* WoThi = ws16 + o; o += (size_t)NPAD_ * 512;
    u16* WoTlo = ws16 + o; o += (size_t)NPAD_ * 512;
    float*    h1buf = (float*)(ws16 + o);
    unsigned* bar   = (unsigned*)(h1buf + 2 * B_ * HID_);

    dim3 blk(256);

    // prep: weight transpose+split (W0, Wout) and embedding gather+split
    wsplit_k<<<dim3(G4_ / 64, 8), blk, 0, stream>>>(W0, W0Thi, W0Tlo, G4_);
    wsplit_k<<<dim3(NPAD_ / 64, 8), blk, 0, stream>>>(Wout, WoThi, WoTlo, VOC_);
    gather_split_k<<<dim3(2048), blk, 0, stream>>>(tokens, emb, Ahi, Alo);

    // G = X0 @ W0 + b0   (split-bf16 MFMA, recurrence-swizzled store)
    gemm_bf16_k<0><<<dim3(G4_ / 128, 64), blk, 0, stream>>>(
        Ahi, Alo, W0Thi, W0Tlo, b0, G, G4_);

    // fused 2-layer recurrence -> Ahi/Alo (h1 bf16)
    hipMemsetAsync(H0x, 0, B_ * HID_ * sizeof(float), stream);    // h0(0) = 0
    hipMemsetAsync(h1buf, 0, B_ * HID_ * sizeof(float), stream);  // h1(0) = 0
    hipMemsetAsync(bar, 0, 1024 * sizeof(unsigned), stream);      // barriers
    fused_rec_k<<<dim3(512), blk, 0, stream>>>(
        G, U0, W1, U1, b1, H0x, Ahi, Alo, h1buf, bar);

    // out[b*T+t, :] = H1 @ W_out + b_out
    gemm_bf16_k<1><<<dim3(NPAD_ / 128, 64), blk, 0, stream>>>(
        Ahi, Alo, WoThi, WoTlo, bout, out, NPAD_);
}

// Round 13
// 2208.724 us; speedup vs baseline: 1.6310x; 1.0030x over previous
//
#include <hip/hip_runtime.h>
#include <math.h>

#define B_    32
#define T_    256
#define HID_  512
#define G4_   2048   // 4*HID
#define VOC_  10000
#define NPAD_ 10112  // 79*128, padded vocab for the bf16 GEMM
#define BH_   (B_ * HID_)

typedef float f32x4 __attribute__((ext_vector_type(4)));
typedef short bf16x8 __attribute__((ext_vector_type(8)));
typedef unsigned short u16;
typedef u16 u16x8 __attribute__((ext_vector_type(8)));

#define AADD(p)  __hip_atomic_fetch_add((p), 1u, __ATOMIC_RELAXED, __HIP_MEMORY_SCOPE_AGENT)
#define ALOAD(p) __hip_atomic_load((p), __ATOMIC_RELAXED, __HIP_MEMORY_SCOPE_AGENT)

// Drain ALL of this wave's outstanding VMEM ops (incl. inline-asm stores the
// compiler's waitcnt pass cannot see) before proceeding. Guide rule #18:
// follow inline-asm waits with sched_barrier so nothing is hoisted past it.
#define DRAIN_STORES() do { \
    asm volatile("s_waitcnt vmcnt(0)" ::: "memory"); \
    __builtin_amdgcn_sched_barrier(0); \
} while (0)

// ---------------- coherent (cross-XCD via IF$) helpers: sc0 sc1 ------------
__device__ __forceinline__ void load4_coherent(const float* p0, const float* p1,
                                               const float* p2, const float* p3,
                                               f32x4& a, f32x4& b, f32x4& c, f32x4& d)
{
    asm volatile(
        "global_load_dwordx4 %0, %4, off sc0 sc1\n\t"
        "global_load_dwordx4 %1, %5, off sc0 sc1\n\t"
        "global_load_dwordx4 %2, %6, off sc0 sc1\n\t"
        "global_load_dwordx4 %3, %7, off sc0 sc1\n\t"
        "s_waitcnt vmcnt(0)"
        : "=&v"(a), "=&v"(b), "=&v"(c), "=&v"(d)
        : "v"(p0), "v"(p1), "v"(p2), "v"(p3)
        : "memory");
}
__device__ __forceinline__ float load_coherent_f32(const float* p)
{
    float v;
    asm volatile("global_load_dword %0, %1, off sc0 sc1\n\ts_waitcnt vmcnt(0)"
                 : "=v"(v) : "v"(p) : "memory");
    return v;
}
__device__ __forceinline__ void store_coherent(float* p, float x)
{
    asm volatile("global_store_dword %0, %1, off sc0 sc1" :: "v"(p), "v"(x) : "memory");
}

__device__ __forceinline__ float fsigm(float x)
{
    float e = exp2f(x * -1.4426950408889634f);
    return __builtin_amdgcn_rcpf(1.f + e);
}
__device__ __forceinline__ float ftanh(float x)
{
    float e = exp2f(x * 2.8853900817779268f);
    return 1.f - 2.f * __builtin_amdgcn_rcpf(e + 1.f);
}

// fp32 -> bf16_hi + bf16_lo (RNE both; a ~= hi + lo with ~16 mantissa bits)
__device__ __forceinline__ void bsplit(float x, u16& hi, u16& lo)
{
    union { float f; unsigned u; } a; a.f = x;
    unsigned r = a.u + 0x7FFFu + ((a.u >> 16) & 1u);
    hi = (u16)(r >> 16);
    union { unsigned u; float f; } hf; hf.u = ((unsigned)hi) << 16;
    union { float f; unsigned u; } b; b.f = x - hf.f;
    unsigned r2 = b.u + 0x7FFFu + ((b.u >> 16) & 1u);
    lo = (u16)(r2 >> 16);
}

// spin until *p >= tgt (monotonic counter), with hang-safety bail
__device__ __forceinline__ void wait_ge(unsigned* p, unsigned tgt)
{
    unsigned g = 0;
    while (ALOAD(p) < tgt) {
        __builtin_amdgcn_s_sleep(2);
        if (++g > 100000000u) break;
    }
}

// ---------------------------------------------------------------------------
// Transpose + split: W [512][N] fp32 -> WT_hi/lo [Npad][512] bf16 (n-major)
// ---------------------------------------------------------------------------
__global__ __launch_bounds__(256)
void wsplit_k(const float* __restrict__ W, u16* __restrict__ Thi,
              u16* __restrict__ Tlo, int N)
{
    __shared__ float tile[64][68];
    const int tid = threadIdx.x;
    const int n0 = blockIdx.x * 64;
    const int k0 = blockIdx.y * 64;

    #pragma unroll
    for (int it = 0; it < 4; ++it) {
        int idx = it * 256 + tid;
        int kr = idx >> 4;
        int nc = (idx & 15) * 4;
        int n  = n0 + nc;
        float4 v = {0.f, 0.f, 0.f, 0.f};
        const float* wp = W + (size_t)(k0 + kr) * N + n;
        if (n + 3 < N) v = *(const float4*)wp;
        else {
            if (n + 0 < N) v.x = wp[0];
            if (n + 1 < N) v.y = wp[1];
            if (n + 2 < N) v.z = wp[2];
            if (n + 3 < N) v.w = wp[3];
        }
        tile[kr][nc + 0] = v.x; tile[kr][nc + 1] = v.y;
        tile[kr][nc + 2] = v.z; tile[kr][nc + 3] = v.w;
    }
    __syncthreads();

    #pragma unroll
    for (int it = 0; it < 2; ++it) {
        int idx = it * 256 + tid;
        int nr = idx >> 3;
        int kb = (idx & 7) * 8;
        u16x8 hv, lv;
        #pragma unroll
        for (int e = 0; e < 8; ++e) {
            u16 h, l;
            bsplit(tile[kb + e][nr], h, l);
            hv[e] = h; lv[e] = l;
        }
        size_t o = (size_t)(n0 + nr) * 512 + k0 + kb;
        *(u16x8*)(Thi + o) = hv;
        *(u16x8*)(Tlo + o) = lv;
    }
}

// ---------------------------------------------------------------------------
// Gather + split: A[r][:] = emb[tokens], r = t*32+b -> Ahi/Alo [8192][512]
// ---------------------------------------------------------------------------
__global__ __launch_bounds__(256)
void gather_split_k(const int* __restrict__ tokens, const float* __restrict__ emb,
                    u16* __restrict__ Ahi, u16* __restrict__ Alo)
{
    const int r    = blockIdx.x * 4 + (threadIdx.x >> 6);
    const int lane = threadIdx.x & 63;
    const int tok  = tokens[(r & 31) * T_ + (r >> 5)];
    const float* src = emb + (size_t)tok * 512 + lane * 8;
    float4 v0 = *(const float4*)(src);
    float4 v1 = *(const float4*)(src + 4);
    const float vv[8] = {v0.x, v0.y, v0.z, v0.w, v1.x, v1.y, v1.z, v1.w};
    u16x8 hv, lv;
    #pragma unroll
    for (int e = 0; e < 8; ++e) { u16 h, l; bsplit(vv[e], h, l); hv[e] = h; lv[e] = l; }
    size_t o = (size_t)r * 512 + lane * 8;
    *(u16x8*)(Ahi + o) = hv;
    *(u16x8*)(Alo + o) = lv;
}

// ---------------------------------------------------------------------------
// Split-bf16 MFMA GEMM (unchanged; proven)
// ---------------------------------------------------------------------------
template<int MODE>
__global__ __launch_bounds__(256)
void gemm_bf16_k(const u16* __restrict__ Ahi, const u16* __restrict__ Alo,
                 const u16* __restrict__ Bhi, const u16* __restrict__ Blo,
                 const float* __restrict__ bias, float* __restrict__ C, int N)
{
    __shared__ u16 As[2][128 * 64];
    __shared__ u16 Bs[2][128 * 64];

    const int tid  = threadIdx.x;
    const int lane = tid & 63;
    const int wid  = tid >> 6;
    const int wm   = wid >> 1;
    const int wn   = wid & 1;
    const int m0   = blockIdx.y * 128;
    const int n0   = blockIdx.x * 128;

    f32x4 acc[4][4];
    #pragma unroll
    for (int i = 0; i < 4; ++i)
        #pragma unroll
        for (int j = 0; j < 4; ++j) acc[i][j] = (f32x4){0.f, 0.f, 0.f, 0.f};

    auto stage = [&](int s, int buf) {
        const int ksel = s >> 3;
        const int koff = (s & 7) * 64;
        const u16* Asrc = (ksel == 2) ? Alo : Ahi;
        const u16* Bsrc = (ksel == 1) ? Blo : Bhi;
        #pragma unroll
        for (int q = 0; q < 4; ++q) {
            const int u   = q * 256 + tid;
            const int row = u >> 3;
            const int kch = (u & 7) ^ (row & 7);
            const u16* ga = Asrc + (size_t)(m0 + row) * 512 + koff + kch * 8;
            const u16* gb = Bsrc + (size_t)(n0 + row) * 512 + koff + kch * 8;
            u16* la = &As[buf][(q * 256 + wid * 64) * 8];
            u16* lb = &Bs[buf][(q * 256 + wid * 64) * 8];
            __builtin_amdgcn_global_load_lds(
                (const __attribute__((address_space(1))) void*)ga,
                (__attribute__((address_space(3))) void*)la, 16, 0, 0);
            __builtin_amdgcn_global_load_lds(
                (const __attribute__((address_space(1))) void*)gb,
                (__attribute__((address_space(3))) void*)lb, 16, 0, 0);
        }
    };

    stage(0, 0);
    for (int s = 0; s < 24; ++s) {
        const int buf = s & 1;
        __syncthreads();
        if (s + 1 < 24) stage(s + 1, buf ^ 1);

        #pragma unroll
        for (int q = 0; q < 2; ++q) {
            bf16x8 af[4], bfr[4];
            #pragma unroll
            for (int mt = 0; mt < 4; ++mt) {
                const int r    = wm * 64 + mt * 16 + (lane & 15);
                const int slot = (q * 4 + (lane >> 4)) ^ (r & 7);
                af[mt] = *(const bf16x8*)&As[buf][r * 64 + slot * 8];
            }
            #pragma unroll
            for (int nt = 0; nt < 4; ++nt) {
                const int rn   = wn * 64 + nt * 16 + (lane & 15);
                const int slot = (q * 4 + (lane >> 4)) ^ (rn & 7);
                bfr[nt] = *(const bf16x8*)&Bs[buf][rn * 64 + slot * 8];
            }
            #pragma unroll
            for (int mt = 0; mt < 4; ++mt)
                #pragma unroll
                for (int nt = 0; nt < 4; ++nt)
                    acc[mt][nt] = __builtin_amdgcn_mfma_f32_16x16x32_bf16(
                        af[mt], bfr[nt], acc[mt][nt], 0, 0, 0);
        }
    }

    #pragma unroll
    for (int mt = 0; mt < 4; ++mt) {
        #pragma unroll
        for (int nt = 0; nt < 4; ++nt) {
            const int c = n0 + wn * 64 + nt * 16 + (lane & 15);
            #pragma unroll
            for (int j = 0; j < 4; ++j) {
                const int r = m0 + wm * 64 + mt * 16 + (lane >> 4) * 4 + j;
                float val = acc[mt][nt][j];
                if constexpr (MODE == 0) {
                    val += bias[c];
                    const int t = r >> 5, bgrp = (r >> 3) & 3, bb = r & 7;
                    const int g = c >> 9, jblk = (c & 511) >> 3, jjs = c & 7;
                    C[(((size_t)t * 4 + bgrp) * 64 + jblk) * 256 + bb * 32 + g * 8 + jjs] = val;
                } else {
                    if (c < VOC_) {
                        val += bias[c];
                        const size_t orow = (size_t)(r & 31) * T_ + (r >> 5);
                        C[orow * VOC_ + c] = val;
                    }
                }
            }
        }
    }
}

// ---------------------------------------------------------------------------
// 3-role pipelined recurrence, UNIFIED code path: 768 blocks x 256 thr.
//   role A (blk 0..255):   z = G[t]  + h0@U0 -> gates -> h0(t) -> H0x[t+1]
//   role B (blk 256..511): z = b1    + h0(t)@W1       -> G1[t]  (raw z)
//   role C (blk 512..767): z = G1[t] + h1@U1 -> gates -> h1(t) -> bf16 out
// r12-identical EXCEPT: explicit DRAIN_STORES() before the arrival barrier.
// r7/r12-fail vs r8/r9-pass analysis: data stores are inline asm, invisible
// to the compiler's waitcnt pass -> a wave could pass __syncthreads and tid0
// could bump the arrival counter while its coherent stores were still in
// flight to IF$. Slow (spilled) builds masked the window; fast builds raced.
// hardware vmcnt counts inline-asm VMEM too, so an explicit vmcnt(0) per
// wave before the barrier closes the hole.
// ---------------------------------------------------------------------------
__global__ __launch_bounds__(256, 1)
void rec3u_k(const float* __restrict__ G, const float* __restrict__ U0,
             const float* __restrict__ W1, const float* __restrict__ U1,
             const float* __restrict__ b1,
             float* __restrict__ H0x,      // [T+1][32][512], slot0 zeroed
             float* __restrict__ G1,       // [T][4][64][256] swizzled
             u16* __restrict__ Ahi, u16* __restrict__ Alo,
             float* __restrict__ h1buf,    // [2][32][512], slot0 zeroed
             unsigned* __restrict__ bar)
{
    __shared__ float lds[8 * 640];       // [b][chunk kc: 16 floats + 4 pad]

    const int tid  = threadIdx.x;
    const int role = blockIdx.x >> 8;    // 0=A, 1=B, 2=C
    const int blk  = blockIdx.x & 255;
    const int bg   = blk >> 6;
    const int cgr  = blk & 63;
    const int j0   = cgr * 8;
    const int b0   = bg * 8;

    const int jj  = tid >> 5;            // 0..7
    const int kc  = tid & 31;            // 0..31 K-chunk
    const int g_  = kc >> 3;             // final gate
    const int bb_ = kc & 7;              // final batch
    const int gofs = bb_ * 32 + g_ * 8 + jj;

    // barrier regions: per (role,bg), 4 shards (16 blocks each) + 1 root
    unsigned* baseA = bar + (0 * 4 + bg) * 80;
    unsigned* baseB = bar + (1 * 4 + bg) * 80;
    unsigned* baseC = bar + (2 * 4 + bg) * 80;
    unsigned* mybase  = (role == 0) ? baseA : (role == 1) ? baseB : baseC;
    unsigned* myshard = mybase + (cgr & 3) * 16;
    unsigned* myroot  = mybase + 64;
    unsigned* rootA = baseA + 64;
    unsigned* rootB = baseB + 64;
    unsigned* rootC = baseC + 64;

    // uniform persistent weights: u[g] = gate g of role's matrix (all K=512)
    const float* Usrc = (role == 0) ? U0 : (role == 1) ? W1 : U1;
    float u[4][16];
    #pragma unroll
    for (int g = 0; g < 4; ++g)
        #pragma unroll
        for (int kk = 0; kk < 16; ++kk)
            u[g][kk] = Usrc[(size_t)(kc * 16 + kk) * G4_ + (g << 9) + j0 + jj];

    float zpre = (role == 0) ? G[((size_t)bg * 64 + cgr) * 256 + gofs] : 0.f;
    const float zb = (role == 1) ? b1[(g_ << 9) + j0 + jj] : 0.f;
    float c_reg = 0.f;

    for (int t = 0; t < T_; ++t) {
        // ---- role-dependent wait (scalar, tid 0 only) ----
        if (tid == 0) {
            if (role == 0)      { if (t > 0) wait_ge(rootA, 4u * (unsigned)t); }
            else if (role == 1) { wait_ge(rootA, 4u * (unsigned)(t + 1)); }
            else {
                wait_ge(rootB, 4u * (unsigned)(t + 1));
                if (t > 0) wait_ge(rootC, 4u * (unsigned)t);
            }
        }
        __syncthreads();

        // ---- UNIFORM stage: src tile [8][512] -> lds (stride-20 padded) ----
        const float* src = (role == 0) ? H0x + (size_t)t * BH_
                         : (role == 1) ? H0x + (size_t)(t + 1) * BH_
                         :               h1buf + (size_t)(t & 1) * BH_;
        {
            const float* p[4]; float* dst[4];
            #pragma unroll
            for (int q = 0; q < 4; ++q) {
                int idx = q * 256 + tid;
                int bL  = idx >> 7;
                int k4  = idx & 127;
                p[q]   = src + (b0 + bL) * HID_ + k4 * 4;
                dst[q] = &lds[bL * 640 + (k4 >> 2) * 20 + (k4 & 3) * 4];
            }
            f32x4 v0, v1, v2, v3;
            load4_coherent(p[0], p[1], p[2], p[3], v0, v1, v2, v3);
            *(f32x4*)dst[0] = v0; *(f32x4*)dst[1] = v1;
            *(f32x4*)dst[2] = v2; *(f32x4*)dst[3] = v3;
        }
        float extra = (role == 2)
            ? load_coherent_f32(G1 + (((size_t)t * 4 + bg) * 64 + cgr) * 256 + gofs)
            : 0.f;
        __syncthreads();

        float zpn = 0.f;
        if (role == 0 && t + 1 < T_)
            zpn = G[(((size_t)(t + 1) * 4 + bg) * 64 + cgr) * 256 + gofs];

        // ---- UNIFORM dot: v[g*8+b] partials over my K-chunk ----
        float v[32];
        #pragma unroll
        for (int s = 0; s < 32; ++s) v[s] = 0.f;
        #pragma unroll
        for (int bb = 0; bb < 8; ++bb) {
            const float* hp = &lds[bb * 640 + kc * 20];
            f32x4 h0v = *(const f32x4*)(hp + 0);
            f32x4 h1v = *(const f32x4*)(hp + 4);
            f32x4 h2v = *(const f32x4*)(hp + 8);
            f32x4 h3v = *(const f32x4*)(hp + 12);
            const float hh[16] = {h0v.x, h0v.y, h0v.z, h0v.w, h1v.x, h1v.y, h1v.z, h1v.w,
                                  h2v.x, h2v.y, h2v.z, h2v.w, h3v.x, h3v.y, h3v.z, h3v.w};
            #pragma unroll
            for (int g = 0; g < 4; ++g)
                #pragma unroll
                for (int kk = 0; kk < 16; ++kk)
                    v[g * 8 + bb] += u[g][kk] * hh[kk];
        }

        // ---- UNIFORM keep/give butterfly reduce-scatter (r6-proven) ----
        float a16[16];
        #pragma unroll
        for (int i = 0; i < 16; ++i) {
            float keep = (kc & 16) ? v[i + 16] : v[i];
            float give = (kc & 16) ? v[i]      : v[i + 16];
            a16[i] = keep + __shfl_xor(give, 16, 32);
        }
        float a8[8];
        #pragma unroll
        for (int i = 0; i < 8; ++i) {
            float keep = (kc & 8) ? a16[i + 8] : a16[i];
            float give = (kc & 8) ? a16[i]     : a16[i + 8];
            a8[i] = keep + __shfl_xor(give, 8, 32);
        }
        float a4[4];
        #pragma unroll
        for (int i = 0; i < 4; ++i) {
            float keep = (kc & 4) ? a8[i + 4] : a8[i];
            float give = (kc & 4) ? a8[i]     : a8[i + 4];
            a4[i] = keep + __shfl_xor(give, 4, 32);
        }
        float a2[2];
        #pragma unroll
        for (int i = 0; i < 2; ++i) {
            float keep = (kc & 2) ? a4[i + 2] : a4[i];
            float give = (kc & 2) ? a4[i]     : a4[i + 2];
            a2[i] = keep + __shfl_xor(give, 2, 32);
        }
        float keep1 = (kc & 1) ? a2[1] : a2[0];
        float give1 = (kc & 1) ? a2[0] : a2[1];
        float z = keep1 + __shfl_xor(give1, 1, 32)
                + ((role == 0) ? zpre : (role == 1) ? zb : extra);
        zpre = zpn;

        // ---- small role epilogues ----
        if (role == 1) {
            store_coherent(&G1[(((size_t)t * 4 + bg) * 64 + cgr) * 256 + gofs], z);
        } else {
            float z8  = __shfl_xor(z, 8, 32);
            float z16 = __shfl_xor(z, 16, 32);
            float z24 = __shfl_xor(z, 24, 32);
            float i_ = fsigm(z);
            float f_ = fsigm(z8);
            float gg = ftanh(z16);
            float o_ = fsigm(z24);
            c_reg = f_ * c_reg + i_ * gg;
            float h_ = o_ * ftanh(c_reg);

            if (g_ == 0) {
                const int brow = b0 + bb_;
                if (role == 0) {
                    store_coherent(&H0x[(size_t)(t + 1) * BH_ + brow * HID_ + j0 + jj], h_);
                } else {
                    store_coherent(&h1buf[(size_t)((t + 1) & 1) * BH_ + brow * HID_ + j0 + jj], h_);
                    u16 hi, lo; bsplit(h_, hi, lo);
                    const size_t o = ((size_t)t * B_ + brow) * HID_ + j0 + jj;
                    Ahi[o] = hi;
                    Alo[o] = lo;
                }
            }
        }

        // ---- arrival: DRAIN this wave's (inline-asm) stores, then barrier,
        //      then tid0 publishes. Hardware vmcnt covers asm VMEM ops. ----
        DRAIN_STORES();
        __syncthreads();
        if (tid == 0) {
            unsigned old = AADD(myshard);
            if (old + 1u == 16u * (unsigned)(t + 1)) AADD(myroot);
        }
    }
}

// ---------------------------------------------------------------------------
extern "C" void kernel_launch(void* const* d_in, const int* in_sizes, int n_in,
                              void* d_out, int out_size, void* d_ws, size_t ws_size,
                              hipStream_t stream)
{
    const int*   tokens = (const int*)  d_in[0];
    const float* emb    = (const float*)d_in[1];
    const float* W0     = (const float*)d_in[2];
    const float* U0     = (const float*)d_in[3];
    const float* b0     = (const float*)d_in[4];
    const float* W1     = (const float*)d_in[5];
    const float* U1     = (const float*)d_in[6];
    const float* b1     = (const float*)d_in[7];
    const float* Wout   = (const float*)d_in[8];
    const float* bout   = (const float*)d_in[9];
    float* out = (float*)d_out;

    // d_out scratch (all dead before the final GEMM overwrites d_out):
    //   G [16.78M fp32] | H0x [257*32*512 = 4.21M] | G1 [16.78M]
    float* G   = out;
    float* H0x = out + (size_t)8192 * 2048;
    float* G1  = H0x + (size_t)(T_ + 1) * BH_;

    u16* ws16 = (u16*)d_ws;
    size_t o = 0;
    u16* Ahi   = ws16 + o; o += (size_t)8192 * 512;
    u16* Alo   = ws16 + o; o += (size_t)8192 * 512;
    u16* W0Thi = ws16 + o; o += (size_t)G4_ * 512;
    u16* W0Tlo = ws16 + o; o += (size_t)G4_ * 512;
    u16* WoThi = ws16 + o; o += (size_t)NPAD_ * 512;
    u16* WoTlo = ws16 + o; o += (size_t)NPAD_ * 512;
    float*    h1buf = (float*)(ws16 + o);
    unsigned* bar   = (unsigned*)(h1buf + 2 * BH_);

    dim3 blk(256);

    // prep: weight transpose+split (W0, Wout) and embedding gather+split
    wsplit_k<<<dim3(G4_ / 64, 8), blk, 0, stream>>>(W0, W0Thi, W0Tlo, G4_);
    wsplit_k<<<dim3(NPAD_ / 64, 8), blk, 0, stream>>>(Wout, WoThi, WoTlo, VOC_);
    gather_split_k<<<dim3(2048), blk, 0, stream>>>(tokens, emb, Ahi, Alo);

    // G = X0 @ W0 + b0   (split-bf16 MFMA, recurrence-swizzled store)
    gemm_bf16_k<0><<<dim3(G4_ / 128, 64), blk, 0, stream>>>(
        Ahi, Alo, W0Thi, W0Tlo, b0, G, G4_);

    // 3-role pipelined recurrence -> Ahi/Alo (h1 bf16)
    hipMemsetAsync(H0x, 0, BH_ * sizeof(float), stream);     // h0(0) = 0
    hipMemsetAsync(h1buf, 0, BH_ * sizeof(float), stream);   // h1(0) = 0
    hipMemsetAsync(bar, 0, 1024 * sizeof(unsigned), stream); // barriers
    rec3u_k<<<dim3(768), blk, 0, stream>>>(
        G, U0, W1, U1, b1, H0x, G1, Ahi, Alo, h1buf, bar);

    // out[b*T+t, :] = H1 @ W_out + b_out
    gemm_bf16_k<1><<<dim3(NPAD_ / 128, 64), blk, 0, stream>>>(
        Ahi, Alo, WoThi, WoTlo, bout, out, NPAD_);
}